// Round 17
// baseline (2412.273 us; speedup 1.0000x reference)
//
#include <hip/hip_runtime.h>
#include <stdint.h>

typedef __attribute__((ext_vector_type(4))) float f32x4;

constexpr float QK_SCALE = 0.08838834764831845f;  // 128^-0.5

#define DEV static __device__ __forceinline__

DEV float rdl(float v, int l){          // wave-uniform lane read (VALU pipe)
  union { float f; int i; } u; u.f = v;
  u.i = __builtin_amdgcn_readlane(u.i, l);
  return u.f;
}

// ===========================================================================
// All-fp32 pipeline (bf16 numerically forbidden: 8-step recursion amplifies
// per-step noise ~1e3-1e4; verified r3-r5). Graph identical to verified r3.
// Stack-memory collapse (verified r3): all K slots identical -> uniform
// memory attention -> Mq/Mk unused; read = PSUM * (Mm @ Mv_full).
// r16 lesson (measured): attn time ~= VALU(140us) + LDS(60-90us) SUM -- the
// pipes don't overlap because one 512-thr block/CU = one barrier domain; all
// waves stall together at each chunk barrier. v10: SAME per-wave work, but
// 256-thr blocks (4 waves, 16 rows), grid 512 -> 2 independent barrier
// domains per CU; block A's compute overlaps block B's staging stalls.
// r14 rule stands: no prefetch pipelining (VGPR spill cliff).
// ===========================================================================

__global__ void k_init32(const float* __restrict__ xr, const float* __restrict__ xi,
                         float* __restrict__ Z, float* __restrict__ Mm,
                         float* __restrict__ PSUM){
  for (int i = blockIdx.x*blockDim.x + threadIdx.x; i < 8192*256; i += gridDim.x*blockDim.x){
    int n = i >> 8, d = i & 255;
    Z[i]  = (d < 128) ? xr[n*128 + d] : xi[n*128 + d - 128];
    Mm[i] = 0.f;
    if (i < 8192) PSUM[i] = 1.f;
  }
}

// ---------------- tiled fp32 GEMM (r6 core, BM templated, r13-verified) -----
template<int EPI, int BM>
__launch_bounds__(256, 2)
__global__ void k_gemm32(const float* __restrict__ A, int nb,
                         const float* __restrict__ W0r, const float* __restrict__ W0i,
                         const float* __restrict__ W1r, const float* __restrict__ W1i,
                         const float* __restrict__ W2r, const float* __restrict__ W2i,
                         float* __restrict__ C, const float* __restrict__ PSUM,
                         const float* __restrict__ bias){
  constexpr int RM = BM / 16;               // rows per thread
  __shared__ float As[32][BM + 4];          // [k][m], padded
  __shared__ float Bs[32][132];             // [k][n], padded
  const int bx = blockIdx.x % nb, by = blockIdx.x / nb;
  const int m0 = by * BM, n0 = bx << 7;
  const int tid = threadIdx.x;
  const int tx = tid & 15, ty = tid >> 4;
  const float* Wr = W0r; const float* Wi = W0i;
  if constexpr (EPI == 0){
    int sec = n0 >> 8;
    Wr = (sec == 0) ? W0r : (sec == 1) ? W1r : W2r;
    Wi = (sec == 0) ? W0i : (sec == 1) ? W1i : W2i;
  }
  const int hn = (n0 >> 7) & 1;
  float acc[RM][8];
  #pragma unroll
  for (int i = 0; i < RM; ++i)
    #pragma unroll
    for (int j = 0; j < 8; ++j) acc[i][j] = 0.f;

  for (int kt = 0; kt < 8; ++kt){
    if (kt) __syncthreads();
    #pragma unroll
    for (int i = 0; i < BM/32; ++i){           // A tile: transpose-scatter
      int c = i*256 + tid;                     // < BM*8 f32x4 units
      int row = c >> 3, k4 = c & 7;
      f32x4 v = *(const f32x4*)&A[(size_t)(m0 + row)*256 + kt*32 + k4*4];
      As[k4*4+0][row] = v.x; As[k4*4+1][row] = v.y;
      As[k4*4+2][row] = v.z; As[k4*4+3][row] = v.w;
    }
    #pragma unroll
    for (int i = 0; i < 4; ++i){               // B tile: on-the-fly Wfull
      int c = i*256 + tid;
      int k = c >> 5, n4 = c & 31;
      int gk = kt*32 + k;
      f32x4 v;
      if constexpr (EPI == 2){
        v = *(const f32x4*)&W0r[(size_t)gk*128 + n4*4];
      } else {
        int hk = gk >> 7, kk = gk & 127;
        const float* src = ((hk ^ hn) == 0) ? Wr : Wi;
        v = *(const f32x4*)&src[(size_t)kk*128 + n4*4];
        if (hk == 1 && hn == 0){ v.x = -v.x; v.y = -v.y; v.z = -v.z; v.w = -v.w; }
      }
      *(f32x4*)&Bs[k][n4*4] = v;
    }
    __syncthreads();
    #pragma unroll 8
    for (int k = 0; k < 32; ++k){
      float a[RM], b[8];
      #pragma unroll
      for (int i4 = 0; i4 < RM/4; ++i4)
        *(f32x4*)&a[i4*4] = *(const f32x4*)&As[k][ty*RM + i4*4];
      *(f32x4*)&b[0] = *(const f32x4*)&Bs[k][tx*8];
      *(f32x4*)&b[4] = *(const f32x4*)&Bs[k][tx*8 + 4];
      #pragma unroll
      for (int i = 0; i < RM; ++i)
        #pragma unroll
        for (int j = 0; j < 8; ++j) acc[i][j] += a[i]*b[j];
    }
  }
  #pragma unroll
  for (int i = 0; i < RM; ++i){
    const int row = m0 + ty*RM + i;
    const int col = n0 + tx*8;
    if constexpr (EPI == 0){
      *(f32x4*)&C[(size_t)row*768 + col]     = *(const f32x4*)&acc[i][0];
      *(f32x4*)&C[(size_t)row*768 + col + 4] = *(const f32x4*)&acc[i][4];
    } else if constexpr (EPI == 1){
      const float s = 0.1f * PSUM[row];
      f32x4 z0 = *(const f32x4*)&C[(size_t)row*256 + col];
      f32x4 z1 = *(const f32x4*)&C[(size_t)row*256 + col + 4];
      z0.x += s*acc[i][0]; z0.y += s*acc[i][1]; z0.z += s*acc[i][2]; z0.w += s*acc[i][3];
      z1.x += s*acc[i][4]; z1.y += s*acc[i][5]; z1.z += s*acc[i][6]; z1.w += s*acc[i][7];
      *(f32x4*)&C[(size_t)row*256 + col]     = z0;
      *(f32x4*)&C[(size_t)row*256 + col + 4] = z1;
    } else {
      f32x4 b0 = *(const f32x4*)&bias[col];
      f32x4 b1 = *(const f32x4*)&bias[col + 4];
      f32x4 o0 = {acc[i][0]+b0.x, acc[i][1]+b0.y, acc[i][2]+b0.z, acc[i][3]+b0.w};
      f32x4 o1 = {acc[i][4]+b1.x, acc[i][5]+b1.y, acc[i][6]+b1.z, acc[i][7]+b1.w};
      *(f32x4*)&C[(size_t)row*128 + col]     = o0;
      *(f32x4*)&C[(size_t)row*128 + col + 4] = o1;
    }
  }
}

// ---------------- fp32 flash attention v10: 2 barrier domains per CU --------
// 256 thr (4 waves), 16 q-rows per block (4 rows/wave, same per-wave work as
// r16), grid 512 -> 2 independent blocks/CU. Q lane-distributed; A/P via
// v_readlane. K staged transposed in LDS (single 16.6 KB buffer); V read
// directly from global (coalesced, L1/L2-resident). Gate fused.
__launch_bounds__(256, 2)
__global__ void k_attn32(const float* __restrict__ QKV, float* __restrict__ ZF,
                         float* __restrict__ Mm, float* __restrict__ PSUM,
                         const float* __restrict__ Wc, const float* __restrict__ bc){
  __shared__ __align__(16) float KV[16*260];    // KT [d][key] chunks
  const int tid = threadIdx.x;
  const int tx = tid & 63;
  const int ty = tid >> 6;                      // wave 0..3, rows ty*4..+3
  const int batch = blockIdx.x >> 6, qt = blockIdx.x & 63;
  const int nbase = batch*1024 + qt*16;
  const int kv0 = batch*1024;

  float qreg[4][4];                             // Q[row ty*4+r][g*64 + lane]
  #pragma unroll
  for (int r = 0; r < 4; ++r)
    #pragma unroll
    for (int g = 0; g < 4; ++g)
      qreg[r][g] = QKV[(size_t)(nbase + ty*4 + r)*768 + g*64 + tx];

  float O[4][4];
  #pragma unroll
  for (int r = 0; r < 4; ++r)
    #pragma unroll
    for (int j = 0; j < 4; ++j) O[r][j] = 0.f;
  float mr[4] = {-3.0e30f, -3.0e30f, -3.0e30f, -3.0e30f};
  float lr[4] = {0.f, 0.f, 0.f, 0.f};

  for (int t = 0; t < 4; ++t){
    const int kb = kv0 + t*256;
    float S[4][4];
    #pragma unroll
    for (int r = 0; r < 4; ++r)
      #pragma unroll
      for (int e = 0; e < 4; ++e) S[r][e] = 0.f;

    #pragma unroll
    for (int gg = 0; gg < 4; ++gg){             // qreg g-index compile-time
      for (int dcc = 0; dcc < 4; ++dcc){        // runtime
        const int dc = gg*4 + dcc;
        __syncthreads();                        // prev chunk readers done
        #pragma unroll
        for (int i = 0; i < 4; ++i){            // stage K chunk transposed
          const int c = i*256 + tid;            // 1024 f32x4 units
          const int key = c & 255, d4 = (c >> 8) & 3;
          f32x4 v = *(const f32x4*)&QKV[(size_t)(kb + key)*768 + 256 + dc*16 + d4*4];
          KV[(d4*4+0)*260 + key] = v.x; KV[(d4*4+1)*260 + key] = v.y;
          KV[(d4*4+2)*260 + key] = v.z; KV[(d4*4+3)*260 + key] = v.w;
        }
        __syncthreads();
        #pragma unroll
        for (int k = 0; k < 16; ++k){
          const int ln = dcc*16 + k;            // (dc*16+k)&63, uniform
          const float a0 = rdl(qreg[0][gg], ln);
          const float a1 = rdl(qreg[1][gg], ln);
          const float a2 = rdl(qreg[2][gg], ln);
          const float a3 = rdl(qreg[3][gg], ln);
          const f32x4 b = *(const f32x4*)&KV[k*260 + tx*4];
          S[0][0] += a0*b.x; S[0][1] += a0*b.y; S[0][2] += a0*b.z; S[0][3] += a0*b.w;
          S[1][0] += a1*b.x; S[1][1] += a1*b.y; S[1][2] += a1*b.z; S[1][3] += a1*b.w;
          S[2][0] += a2*b.x; S[2][1] += a2*b.y; S[2][2] += a2*b.z; S[2][3] += a2*b.w;
          S[3][0] += a3*b.x; S[3][1] += a3*b.y; S[3][2] += a3*b.z; S[3][3] += a3*b.w;
        }
      }
    }
    // ---- online softmax: row = wave (lane tx owns keys tx*4..+3) ----
    float pp[4][4];
    #pragma unroll
    for (int r = 0; r < 4; ++r){
      #pragma unroll
      for (int e = 0; e < 4; ++e) S[r][e] *= QK_SCALE;
      float tm = fmaxf(fmaxf(S[r][0], S[r][1]), fmaxf(S[r][2], S[r][3]));
      tm = fmaxf(tm, __shfl_xor(tm, 1));
      tm = fmaxf(tm, __shfl_xor(tm, 2));
      tm = fmaxf(tm, __shfl_xor(tm, 4));
      tm = fmaxf(tm, __shfl_xor(tm, 8));
      tm = fmaxf(tm, __shfl_xor(tm, 16));
      tm = fmaxf(tm, __shfl_xor(tm, 32));
      const float mn = fmaxf(mr[r], tm);
      const float al = expf(mr[r] - mn);
      pp[r][0] = expf(S[r][0] - mn); pp[r][1] = expf(S[r][1] - mn);
      pp[r][2] = expf(S[r][2] - mn); pp[r][3] = expf(S[r][3] - mn);
      float rs = (pp[r][0] + pp[r][1]) + (pp[r][2] + pp[r][3]);
      rs += __shfl_xor(rs, 1); rs += __shfl_xor(rs, 2);
      rs += __shfl_xor(rs, 4); rs += __shfl_xor(rs, 8);
      rs += __shfl_xor(rs, 16); rs += __shfl_xor(rs, 32);
      lr[r] = lr[r]*al + rs;
      mr[r] = mn;
      O[r][0] *= al; O[r][1] *= al; O[r][2] *= al; O[r][3] *= al;
    }
    // ---- PV: V direct from global (coalesced, L1-resident); P via rdl ----
    const float* __restrict__ Vb = QKV + (size_t)kb*768 + 512 + tx*4;
    #pragma unroll 1
    for (int ks = 0; ks < 16; ++ks){
      #pragma unroll
      for (int kg = 0; kg < 4; ++kg){
        const int ln = ks*4 + kg;               // lane owning these 4 keys
        const float* vp = Vb + (size_t)(ks*16 + kg*4)*768;
        const f32x4 v0 = *(const f32x4*)(vp);
        const f32x4 v1 = *(const f32x4*)(vp + 768);
        const f32x4 v2 = *(const f32x4*)(vp + 1536);
        const f32x4 v3 = *(const f32x4*)(vp + 2304);
        #pragma unroll
        for (int r = 0; r < 4; ++r){
          const float a0 = rdl(pp[r][0], ln);
          const float a1 = rdl(pp[r][1], ln);
          const float a2 = rdl(pp[r][2], ln);
          const float a3 = rdl(pp[r][3], ln);
          O[r][0] += a0*v0.x + a1*v1.x + a2*v2.x + a3*v3.x;
          O[r][1] += a0*v0.y + a1*v1.y + a2*v2.y + a3*v3.y;
          O[r][2] += a0*v0.z + a1*v1.z + a2*v2.z + a3*v3.z;
          O[r][3] += a0*v0.w + a1*v1.w + a2*v2.w + a3*v3.w;
        }
      }
    }
  }
  // ---- epilogue: normalize + fused gate + memory/pointer update ----
  const float bc0 = bc[0], bc1 = bc[1], bc2 = bc[2];
  #pragma unroll
  for (int r = 0; r < 4; ++r){
    const float inv = 1.f / lr[r];
    #pragma unroll
    for (int j = 0; j < 4; ++j) O[r][j] *= inv;
    float d0 = 0.f, d1 = 0.f, d2 = 0.f;
    #pragma unroll
    for (int j = 0; j < 4; ++j){
      const int dim = tx*4 + j;
      const float z = O[r][j];
      d0 += z*Wc[dim*3 + 0]; d1 += z*Wc[dim*3 + 1]; d2 += z*Wc[dim*3 + 2];
    }
    d0 += __shfl_xor(d0,1); d0 += __shfl_xor(d0,2); d0 += __shfl_xor(d0,4);
    d0 += __shfl_xor(d0,8); d0 += __shfl_xor(d0,16); d0 += __shfl_xor(d0,32);
    d1 += __shfl_xor(d1,1); d1 += __shfl_xor(d1,2); d1 += __shfl_xor(d1,4);
    d1 += __shfl_xor(d1,8); d1 += __shfl_xor(d1,16); d1 += __shfl_xor(d1,32);
    d2 += __shfl_xor(d2,1); d2 += __shfl_xor(d2,2); d2 += __shfl_xor(d2,4);
    d2 += __shfl_xor(d2,8); d2 += __shfl_xor(d2,16); d2 += __shfl_xor(d2,32);
    const float g0 = 1.f/(1.f + expf(-(d0 + bc0)));
    const float g1 = 1.f/(1.f + expf(-(d1 + bc1)));
    const float g2 = 1.f/(1.f + expf(-(d2 + bc2)));
    const float tt = g0 + g1 + g2, tot = tt + 1e-6f;
    const float push = g0/tot;
    const int row = nbase + ty*4 + r;
    if (tx == 0) PSUM[row] *= tt/tot;
    const size_t idx = (size_t)row*256 + tx*4;
    f32x4 z0 = {O[r][0], O[r][1], O[r][2], O[r][3]};
    f32x4 m0 = *(const f32x4*)&Mm[idx];
    m0.x += push*(z0.x - m0.x); m0.y += push*(z0.y - m0.y);
    m0.z += push*(z0.z - m0.z); m0.w += push*(z0.w - m0.w);
    *(f32x4*)&Mm[idx] = m0;
    *(f32x4*)&ZF[idx] = z0;
  }
}

// ---------------------------------------------------------------------------
extern "C" void kernel_launch(void* const* d_in, const int* in_sizes, int n_in,
                              void* d_out, int out_size, void* d_ws, size_t ws_size,
                              hipStream_t stream){
  (void)in_sizes; (void)n_in; (void)out_size; (void)ws_size;
  const float* xr   = (const float*)d_in[0];
  const float* xi   = (const float*)d_in[1];
  const float* Wq_r = (const float*)d_in[2];
  const float* Wq_i = (const float*)d_in[3];
  const float* Wk_r = (const float*)d_in[4];
  const float* Wk_i = (const float*)d_in[5];
  const float* Wv_r = (const float*)d_in[6];
  const float* Wv_i = (const float*)d_in[7];
  // d_in[8..11] (Mq_*, Mk_*) unused: all stack slots identical -> memory
  // attention exactly uniform regardless of its q/k projections (verified r3).
  const float* Mv_r = (const float*)d_in[12];
  const float* Mv_i = (const float*)d_in[13];
  const float* Wc   = (const float*)d_in[14];
  const float* bc   = (const float*)d_in[15];
  const float* Wo   = (const float*)d_in[16];
  const float* bo   = (const float*)d_in[17];

  // Workspace layout identical to verified round 3/6 (41,975,808 B).
  uint8_t* w = (uint8_t*)d_ws;
  float* Z    = (float*)w; w += (size_t)8192*256*4;   // state; aliased as ZF
  float* QKV  = (float*)w; w += (size_t)8192*768*4;
  float* Mm   = (float*)w; w += (size_t)8192*256*4;
  float* PSUM = (float*)w; w += (size_t)8192*4;
  float* ZF   = Z;  // safe alias: state dead once proj consumed it.

  k_init32<<<dim3(1024), dim3(256), 0, stream>>>(xr, xi, Z, Mm, PSUM);
  for (int t = 0; t < 8; ++t){
    k_gemm32<0,64><<<dim3(768), dim3(256), 0, stream>>>(Z, 6,
        Wq_r, Wq_i, Wk_r, Wk_i, Wv_r, Wv_i, QKV, nullptr, nullptr);
    k_attn32<<<dim3(512), dim3(256), 0, stream>>>(QKV, ZF, Mm, PSUM, Wc, bc);
    k_gemm32<1,64><<<dim3(256), dim3(256), 0, stream>>>(Mm, 2,
        Mv_r, Mv_i, nullptr, nullptr, nullptr, nullptr, Z, PSUM, nullptr);
  }
  k_gemm32<2,128><<<dim3(64), dim3(256), 0, stream>>>(Z, 1,
      Wo, nullptr, nullptr, nullptr, nullptr, nullptr, (float*)d_out, nullptr, bo);
}

// Round 18
// 2151.703 us; speedup vs baseline: 1.1211x; 1.1211x over previous
//
#include <hip/hip_runtime.h>
#include <stdint.h>

typedef __attribute__((ext_vector_type(4))) float f32x4;

constexpr float QK_SCALE = 0.08838834764831845f;  // 128^-0.5

#define DEV static __device__ __forceinline__

DEV float rdl(float v, int l){          // wave-uniform lane read (VALU pipe)
  union { float f; int i; } u; u.f = v;
  u.i = __builtin_amdgcn_readlane(u.i, l);
  return u.f;
}

// ===========================================================================
// All-fp32 pipeline (bf16 numerically forbidden: 8-step recursion amplifies
// per-step noise ~1e3-1e4; verified r3-r5). Graph identical to verified r3.
// Stack-memory collapse (verified r3): all K slots identical -> uniform
// memory attention -> Mq/Mk unused; read = PSUM * (Mm @ Mv_full).
// r14-r17 lessons (measured): every restructuring of r13 lost -- dbuf
// prefetch spills (128-VGPR cliff on 512-thr), more waves raises per-row LDS
// traffic, global-V and 2-block domains are neutral/worse. r13 = optimum.
// This round: r13 verbatim except chunk width 16->32 dims/keys -- halves the
// number of staging-latency exposures (64->32 barrier pairs per tile) with
// no new cross-loop live ranges (stage burst = 4 f32x4, transient).
// ===========================================================================

__global__ void k_init32(const float* __restrict__ xr, const float* __restrict__ xi,
                         float* __restrict__ Z, float* __restrict__ Mm,
                         float* __restrict__ PSUM){
  for (int i = blockIdx.x*blockDim.x + threadIdx.x; i < 8192*256; i += gridDim.x*blockDim.x){
    int n = i >> 8, d = i & 255;
    Z[i]  = (d < 128) ? xr[n*128 + d] : xi[n*128 + d - 128];
    Mm[i] = 0.f;
    if (i < 8192) PSUM[i] = 1.f;
  }
}

// ---------------- tiled fp32 GEMM (r6 core, BM templated, r13-verified) -----
template<int EPI, int BM>
__launch_bounds__(256, 2)
__global__ void k_gemm32(const float* __restrict__ A, int nb,
                         const float* __restrict__ W0r, const float* __restrict__ W0i,
                         const float* __restrict__ W1r, const float* __restrict__ W1i,
                         const float* __restrict__ W2r, const float* __restrict__ W2i,
                         float* __restrict__ C, const float* __restrict__ PSUM,
                         const float* __restrict__ bias){
  constexpr int RM = BM / 16;               // rows per thread
  __shared__ float As[32][BM + 4];          // [k][m], padded
  __shared__ float Bs[32][132];             // [k][n], padded
  const int bx = blockIdx.x % nb, by = blockIdx.x / nb;
  const int m0 = by * BM, n0 = bx << 7;
  const int tid = threadIdx.x;
  const int tx = tid & 15, ty = tid >> 4;
  const float* Wr = W0r; const float* Wi = W0i;
  if constexpr (EPI == 0){
    int sec = n0 >> 8;
    Wr = (sec == 0) ? W0r : (sec == 1) ? W1r : W2r;
    Wi = (sec == 0) ? W0i : (sec == 1) ? W1i : W2i;
  }
  const int hn = (n0 >> 7) & 1;
  float acc[RM][8];
  #pragma unroll
  for (int i = 0; i < RM; ++i)
    #pragma unroll
    for (int j = 0; j < 8; ++j) acc[i][j] = 0.f;

  for (int kt = 0; kt < 8; ++kt){
    if (kt) __syncthreads();
    #pragma unroll
    for (int i = 0; i < BM/32; ++i){           // A tile: transpose-scatter
      int c = i*256 + tid;                     // < BM*8 f32x4 units
      int row = c >> 3, k4 = c & 7;
      f32x4 v = *(const f32x4*)&A[(size_t)(m0 + row)*256 + kt*32 + k4*4];
      As[k4*4+0][row] = v.x; As[k4*4+1][row] = v.y;
      As[k4*4+2][row] = v.z; As[k4*4+3][row] = v.w;
    }
    #pragma unroll
    for (int i = 0; i < 4; ++i){               // B tile: on-the-fly Wfull
      int c = i*256 + tid;
      int k = c >> 5, n4 = c & 31;
      int gk = kt*32 + k;
      f32x4 v;
      if constexpr (EPI == 2){
        v = *(const f32x4*)&W0r[(size_t)gk*128 + n4*4];
      } else {
        int hk = gk >> 7, kk = gk & 127;
        const float* src = ((hk ^ hn) == 0) ? Wr : Wi;
        v = *(const f32x4*)&src[(size_t)kk*128 + n4*4];
        if (hk == 1 && hn == 0){ v.x = -v.x; v.y = -v.y; v.z = -v.z; v.w = -v.w; }
      }
      *(f32x4*)&Bs[k][n4*4] = v;
    }
    __syncthreads();
    #pragma unroll 8
    for (int k = 0; k < 32; ++k){
      float a[RM], b[8];
      #pragma unroll
      for (int i4 = 0; i4 < RM/4; ++i4)
        *(f32x4*)&a[i4*4] = *(const f32x4*)&As[k][ty*RM + i4*4];
      *(f32x4*)&b[0] = *(const f32x4*)&Bs[k][tx*8];
      *(f32x4*)&b[4] = *(const f32x4*)&Bs[k][tx*8 + 4];
      #pragma unroll
      for (int i = 0; i < RM; ++i)
        #pragma unroll
        for (int j = 0; j < 8; ++j) acc[i][j] += a[i]*b[j];
    }
  }
  #pragma unroll
  for (int i = 0; i < RM; ++i){
    const int row = m0 + ty*RM + i;
    const int col = n0 + tx*8;
    if constexpr (EPI == 0){
      *(f32x4*)&C[(size_t)row*768 + col]     = *(const f32x4*)&acc[i][0];
      *(f32x4*)&C[(size_t)row*768 + col + 4] = *(const f32x4*)&acc[i][4];
    } else if constexpr (EPI == 1){
      const float s = 0.1f * PSUM[row];
      f32x4 z0 = *(const f32x4*)&C[(size_t)row*256 + col];
      f32x4 z1 = *(const f32x4*)&C[(size_t)row*256 + col + 4];
      z0.x += s*acc[i][0]; z0.y += s*acc[i][1]; z0.z += s*acc[i][2]; z0.w += s*acc[i][3];
      z1.x += s*acc[i][4]; z1.y += s*acc[i][5]; z1.z += s*acc[i][6]; z1.w += s*acc[i][7];
      *(f32x4*)&C[(size_t)row*256 + col]     = z0;
      *(f32x4*)&C[(size_t)row*256 + col + 4] = z1;
    } else {
      f32x4 b0 = *(const f32x4*)&bias[col];
      f32x4 b1 = *(const f32x4*)&bias[col + 4];
      f32x4 o0 = {acc[i][0]+b0.x, acc[i][1]+b0.y, acc[i][2]+b0.z, acc[i][3]+b0.w};
      f32x4 o1 = {acc[i][4]+b1.x, acc[i][5]+b1.y, acc[i][6]+b1.z, acc[i][7]+b1.w};
      *(f32x4*)&C[(size_t)row*128 + col]     = o0;
      *(f32x4*)&C[(size_t)row*128 + col + 4] = o1;
    }
  }
}

// ---------------- fp32 flash attention v11: r13 core, 32-wide chunks --------
// 512 thr: ty = tid>>6 (wave, rows ty*4..+3), tx = tid&63 (4 keys / 4 dims).
// Q lane-distributed; A/P via v_readlane (VALU pipe). K staged transposed in
// LDS, V staged natural, single 33.3 KB chunk buffer, 32 dims/keys per chunk
// (half the barrier pairs of r13). No prefetch (r14 spill rule). Gate fused.
__launch_bounds__(512, 1)
__global__ void k_attn32(const float* __restrict__ QKV, float* __restrict__ ZF,
                         float* __restrict__ Mm, float* __restrict__ PSUM,
                         const float* __restrict__ Wc, const float* __restrict__ bc){
  __shared__ __align__(16) float KV[32*260];    // KT [d][key] | V [key][d]
  const int tid = threadIdx.x;
  const int tx = tid & 63;
  const int ty = tid >> 6;
  const int batch = blockIdx.x >> 5, qt = blockIdx.x & 31;
  const int nbase = batch*1024 + qt*32;
  const int kv0 = batch*1024;

  float qreg[4][4];                             // Q[row ty*4+r][g*64 + lane]
  #pragma unroll
  for (int r = 0; r < 4; ++r)
    #pragma unroll
    for (int g = 0; g < 4; ++g)
      qreg[r][g] = QKV[(size_t)(nbase + ty*4 + r)*768 + g*64 + tx];

  float O[4][4];
  #pragma unroll
  for (int r = 0; r < 4; ++r)
    #pragma unroll
    for (int j = 0; j < 4; ++j) O[r][j] = 0.f;
  float mr[4] = {-3.0e30f, -3.0e30f, -3.0e30f, -3.0e30f};
  float lr[4] = {0.f, 0.f, 0.f, 0.f};

  for (int t = 0; t < 4; ++t){
    const int kb = kv0 + t*256;
    float S[4][4];
    #pragma unroll
    for (int r = 0; r < 4; ++r)
      #pragma unroll
      for (int e = 0; e < 4; ++e) S[r][e] = 0.f;

    #pragma unroll
    for (int gg = 0; gg < 4; ++gg){             // qreg g-index compile-time
      for (int dcc = 0; dcc < 2; ++dcc){        // runtime: 32-dim chunks
        const int dc = gg*2 + dcc;
        __syncthreads();                        // prev chunk readers done
        #pragma unroll
        for (int i = 0; i < 4; ++i){            // stage K chunk transposed
          const int c = i*512 + tid;            // 2048 f32x4 units
          const int key = c & 255, d4 = c >> 8; // d4 0..7
          f32x4 v = *(const f32x4*)&QKV[(size_t)(kb + key)*768 + 256 + dc*32 + d4*4];
          KV[(d4*4+0)*260 + key] = v.x; KV[(d4*4+1)*260 + key] = v.y;
          KV[(d4*4+2)*260 + key] = v.z; KV[(d4*4+3)*260 + key] = v.w;
        }
        __syncthreads();
        #pragma unroll
        for (int k = 0; k < 32; ++k){
          const int ln = dcc*32 + k;            // (dc*32+k)&63, uniform
          const float a0 = rdl(qreg[0][gg], ln);
          const float a1 = rdl(qreg[1][gg], ln);
          const float a2 = rdl(qreg[2][gg], ln);
          const float a3 = rdl(qreg[3][gg], ln);
          const f32x4 b = *(const f32x4*)&KV[k*260 + tx*4];
          S[0][0] += a0*b.x; S[0][1] += a0*b.y; S[0][2] += a0*b.z; S[0][3] += a0*b.w;
          S[1][0] += a1*b.x; S[1][1] += a1*b.y; S[1][2] += a1*b.z; S[1][3] += a1*b.w;
          S[2][0] += a2*b.x; S[2][1] += a2*b.y; S[2][2] += a2*b.z; S[2][3] += a2*b.w;
          S[3][0] += a3*b.x; S[3][1] += a3*b.y; S[3][2] += a3*b.z; S[3][3] += a3*b.w;
        }
      }
    }
    // ---- online softmax: row = wave (lane tx owns keys tx*4..+3) ----
    float pp[4][4];
    #pragma unroll
    for (int r = 0; r < 4; ++r){
      #pragma unroll
      for (int e = 0; e < 4; ++e) S[r][e] *= QK_SCALE;
      float tm = fmaxf(fmaxf(S[r][0], S[r][1]), fmaxf(S[r][2], S[r][3]));
      tm = fmaxf(tm, __shfl_xor(tm, 1));
      tm = fmaxf(tm, __shfl_xor(tm, 2));
      tm = fmaxf(tm, __shfl_xor(tm, 4));
      tm = fmaxf(tm, __shfl_xor(tm, 8));
      tm = fmaxf(tm, __shfl_xor(tm, 16));
      tm = fmaxf(tm, __shfl_xor(tm, 32));
      const float mn = fmaxf(mr[r], tm);
      const float al = expf(mr[r] - mn);
      pp[r][0] = expf(S[r][0] - mn); pp[r][1] = expf(S[r][1] - mn);
      pp[r][2] = expf(S[r][2] - mn); pp[r][3] = expf(S[r][3] - mn);
      float rs = (pp[r][0] + pp[r][1]) + (pp[r][2] + pp[r][3]);
      rs += __shfl_xor(rs, 1); rs += __shfl_xor(rs, 2);
      rs += __shfl_xor(rs, 4); rs += __shfl_xor(rs, 8);
      rs += __shfl_xor(rs, 16); rs += __shfl_xor(rs, 32);
      lr[r] = lr[r]*al + rs;
      mr[r] = mn;
      O[r][0] *= al; O[r][1] *= al; O[r][2] *= al; O[r][3] *= al;
    }
    // ---- PV over 8 chunks of 32 keys; P via readlane ----
    for (int ks = 0; ks < 8; ++ks){
      __syncthreads();                          // prev chunk readers done
      #pragma unroll
      for (int i = 0; i < 4; ++i){              // stage V chunk natural
        const int c = i*512 + tid;              // 2048 f32x4 units
        const int key = c >> 6, d4 = c & 63;    // key 0..31
        *(f32x4*)&KV[key*260 + d4*4] =
            *(const f32x4*)&QKV[(size_t)(kb + ks*32 + key)*768 + 512 + d4*4];
      }
      __syncthreads();
      #pragma unroll
      for (int kg = 0; kg < 8; ++kg){
        const int ln = ks*8 + kg;               // lane owning these 4 keys
        #pragma unroll
        for (int k2 = 0; k2 < 4; ++k2){
          const float a0 = rdl(pp[0][k2], ln);
          const float a1 = rdl(pp[1][k2], ln);
          const float a2 = rdl(pp[2][k2], ln);
          const float a3 = rdl(pp[3][k2], ln);
          const f32x4 v = *(const f32x4*)&KV[(kg*4+k2)*260 + tx*4];
          O[0][0] += a0*v.x; O[0][1] += a0*v.y; O[0][2] += a0*v.z; O[0][3] += a0*v.w;
          O[1][0] += a1*v.x; O[1][1] += a1*v.y; O[1][2] += a1*v.z; O[1][3] += a1*v.w;
          O[2][0] += a2*v.x; O[2][1] += a2*v.y; O[2][2] += a2*v.z; O[2][3] += a2*v.w;
          O[3][0] += a3*v.x; O[3][1] += a3*v.y; O[3][2] += a3*v.z; O[3][3] += a3*v.w;
        }
      }
    }
  }
  // ---- epilogue: normalize + fused gate + memory/pointer update ----
  const float bc0 = bc[0], bc1 = bc[1], bc2 = bc[2];
  #pragma unroll
  for (int r = 0; r < 4; ++r){
    const float inv = 1.f / lr[r];
    #pragma unroll
    for (int j = 0; j < 4; ++j) O[r][j] *= inv;
    float d0 = 0.f, d1 = 0.f, d2 = 0.f;
    #pragma unroll
    for (int j = 0; j < 4; ++j){
      const int dim = tx*4 + j;
      const float z = O[r][j];
      d0 += z*Wc[dim*3 + 0]; d1 += z*Wc[dim*3 + 1]; d2 += z*Wc[dim*3 + 2];
    }
    d0 += __shfl_xor(d0,1); d0 += __shfl_xor(d0,2); d0 += __shfl_xor(d0,4);
    d0 += __shfl_xor(d0,8); d0 += __shfl_xor(d0,16); d0 += __shfl_xor(d0,32);
    d1 += __shfl_xor(d1,1); d1 += __shfl_xor(d1,2); d1 += __shfl_xor(d1,4);
    d1 += __shfl_xor(d1,8); d1 += __shfl_xor(d1,16); d1 += __shfl_xor(d1,32);
    d2 += __shfl_xor(d2,1); d2 += __shfl_xor(d2,2); d2 += __shfl_xor(d2,4);
    d2 += __shfl_xor(d2,8); d2 += __shfl_xor(d2,16); d2 += __shfl_xor(d2,32);
    const float g0 = 1.f/(1.f + expf(-(d0 + bc0)));
    const float g1 = 1.f/(1.f + expf(-(d1 + bc1)));
    const float g2 = 1.f/(1.f + expf(-(d2 + bc2)));
    const float tt = g0 + g1 + g2, tot = tt + 1e-6f;
    const float push = g0/tot;
    const int row = nbase + ty*4 + r;
    if (tx == 0) PSUM[row] *= tt/tot;
    const size_t idx = (size_t)row*256 + tx*4;
    f32x4 z0 = {O[r][0], O[r][1], O[r][2], O[r][3]};
    f32x4 m0 = *(const f32x4*)&Mm[idx];
    m0.x += push*(z0.x - m0.x); m0.y += push*(z0.y - m0.y);
    m0.z += push*(z0.z - m0.z); m0.w += push*(z0.w - m0.w);
    *(f32x4*)&Mm[idx] = m0;
    *(f32x4*)&ZF[idx] = z0;
  }
}

// ---------------------------------------------------------------------------
extern "C" void kernel_launch(void* const* d_in, const int* in_sizes, int n_in,
                              void* d_out, int out_size, void* d_ws, size_t ws_size,
                              hipStream_t stream){
  (void)in_sizes; (void)n_in; (void)out_size; (void)ws_size;
  const float* xr   = (const float*)d_in[0];
  const float* xi   = (const float*)d_in[1];
  const float* Wq_r = (const float*)d_in[2];
  const float* Wq_i = (const float*)d_in[3];
  const float* Wk_r = (const float*)d_in[4];
  const float* Wk_i = (const float*)d_in[5];
  const float* Wv_r = (const float*)d_in[6];
  const float* Wv_i = (const float*)d_in[7];
  // d_in[8..11] (Mq_*, Mk_*) unused: all stack slots identical -> memory
  // attention exactly uniform regardless of its q/k projections (verified r3).
  const float* Mv_r = (const float*)d_in[12];
  const float* Mv_i = (const float*)d_in[13];
  const float* Wc   = (const float*)d_in[14];
  const float* bc   = (const float*)d_in[15];
  const float* Wo   = (const float*)d_in[16];
  const float* bo   = (const float*)d_in[17];

  // Workspace layout identical to verified round 3/6 (41,975,808 B).
  uint8_t* w = (uint8_t*)d_ws;
  float* Z    = (float*)w; w += (size_t)8192*256*4;   // state; aliased as ZF
  float* QKV  = (float*)w; w += (size_t)8192*768*4;
  float* Mm   = (float*)w; w += (size_t)8192*256*4;
  float* PSUM = (float*)w; w += (size_t)8192*4;
  float* ZF   = Z;  // safe alias: state dead once proj consumed it.

  k_init32<<<dim3(1024), dim3(256), 0, stream>>>(xr, xi, Z, Mm, PSUM);
  for (int t = 0; t < 8; ++t){
    k_gemm32<0,64><<<dim3(768), dim3(256), 0, stream>>>(Z, 6,
        Wq_r, Wq_i, Wk_r, Wk_i, Wv_r, Wv_i, QKV, nullptr, nullptr);
    k_attn32<<<dim3(256), dim3(512), 0, stream>>>(QKV, ZF, Mm, PSUM, Wc, bc);
    k_gemm32<1,64><<<dim3(256), dim3(256), 0, stream>>>(Mm, 2,
        Mv_r, Mv_i, nullptr, nullptr, nullptr, nullptr, Z, PSUM, nullptr);
  }
  k_gemm32<2,128><<<dim3(64), dim3(256), 0, stream>>>(Z, 1,
      Wo, nullptr, nullptr, nullptr, nullptr, nullptr, (float*)d_out, nullptr, bo);
}

// Round 19
// 2111.055 us; speedup vs baseline: 1.1427x; 1.0193x over previous
//
#include <hip/hip_runtime.h>
#include <stdint.h>

typedef __attribute__((ext_vector_type(4))) float f32x4;

constexpr float QK_SCALE = 0.08838834764831845f;  // 128^-0.5

#define DEV static __device__ __forceinline__

DEV float rdl(float v, int l){          // wave-uniform lane read (VALU pipe)
  union { float f; int i; } u; u.f = v;
  u.i = __builtin_amdgcn_readlane(u.i, l);
  return u.f;
}

// ===========================================================================
// All-fp32 pipeline (bf16 numerically forbidden: 8-step recursion amplifies
// per-step noise ~1e3-1e4; verified r3-r5). Graph identical to verified r3.
// Stack-memory collapse (verified r3): all K slots identical -> uniform
// memory attention -> Mq/Mk unused; read = PSUM * (Mm @ Mv_full).
// FINAL (r19): byte-identical restore of the round-13 measured optimum
// (2.114 ms; attn 206us, VGPR 84, no spills, conflicts 0). The r14-r18
// sweep proved every neighboring structure is neutral or worse:
//   r14 dbuf prefetch  -> 128-VGPR spill cliff (WRITE 16KB->726MB), +108%
//   r15 2x occupancy   -> per-row LDS traffic doubles, +11%
//   r16 global-V PV    -> VALU addressing offsets LDS savings, +6%
//   r17 2 barrier doms -> per-wave staging doubles, +20%
//   r18 32-wide chunks -> same total exposed latency, +3%
// Attention budget: ~124us VALU issue + ~80us unhideable staging latency
// (toolchain pins 512-thr kernels at 128 VGPR; pipelining spills).
// ===========================================================================

__global__ void k_init32(const float* __restrict__ xr, const float* __restrict__ xi,
                         float* __restrict__ Z, float* __restrict__ Mm,
                         float* __restrict__ PSUM){
  for (int i = blockIdx.x*blockDim.x + threadIdx.x; i < 8192*256; i += gridDim.x*blockDim.x){
    int n = i >> 8, d = i & 255;
    Z[i]  = (d < 128) ? xr[n*128 + d] : xi[n*128 + d - 128];
    Mm[i] = 0.f;
    if (i < 8192) PSUM[i] = 1.f;
  }
}

// ---------------- tiled fp32 GEMM (r6 core, BM templated, r13-verified) -----
template<int EPI, int BM>
__launch_bounds__(256, 2)
__global__ void k_gemm32(const float* __restrict__ A, int nb,
                         const float* __restrict__ W0r, const float* __restrict__ W0i,
                         const float* __restrict__ W1r, const float* __restrict__ W1i,
                         const float* __restrict__ W2r, const float* __restrict__ W2i,
                         float* __restrict__ C, const float* __restrict__ PSUM,
                         const float* __restrict__ bias){
  constexpr int RM = BM / 16;               // rows per thread
  __shared__ float As[32][BM + 4];          // [k][m], padded
  __shared__ float Bs[32][132];             // [k][n], padded
  const int bx = blockIdx.x % nb, by = blockIdx.x / nb;
  const int m0 = by * BM, n0 = bx << 7;
  const int tid = threadIdx.x;
  const int tx = tid & 15, ty = tid >> 4;
  const float* Wr = W0r; const float* Wi = W0i;
  if constexpr (EPI == 0){
    int sec = n0 >> 8;
    Wr = (sec == 0) ? W0r : (sec == 1) ? W1r : W2r;
    Wi = (sec == 0) ? W0i : (sec == 1) ? W1i : W2i;
  }
  const int hn = (n0 >> 7) & 1;
  float acc[RM][8];
  #pragma unroll
  for (int i = 0; i < RM; ++i)
    #pragma unroll
    for (int j = 0; j < 8; ++j) acc[i][j] = 0.f;

  for (int kt = 0; kt < 8; ++kt){
    if (kt) __syncthreads();
    #pragma unroll
    for (int i = 0; i < BM/32; ++i){           // A tile: transpose-scatter
      int c = i*256 + tid;                     // < BM*8 f32x4 units
      int row = c >> 3, k4 = c & 7;
      f32x4 v = *(const f32x4*)&A[(size_t)(m0 + row)*256 + kt*32 + k4*4];
      As[k4*4+0][row] = v.x; As[k4*4+1][row] = v.y;
      As[k4*4+2][row] = v.z; As[k4*4+3][row] = v.w;
    }
    #pragma unroll
    for (int i = 0; i < 4; ++i){               // B tile: on-the-fly Wfull
      int c = i*256 + tid;
      int k = c >> 5, n4 = c & 31;
      int gk = kt*32 + k;
      f32x4 v;
      if constexpr (EPI == 2){
        v = *(const f32x4*)&W0r[(size_t)gk*128 + n4*4];
      } else {
        int hk = gk >> 7, kk = gk & 127;
        const float* src = ((hk ^ hn) == 0) ? Wr : Wi;
        v = *(const f32x4*)&src[(size_t)kk*128 + n4*4];
        if (hk == 1 && hn == 0){ v.x = -v.x; v.y = -v.y; v.z = -v.z; v.w = -v.w; }
      }
      *(f32x4*)&Bs[k][n4*4] = v;
    }
    __syncthreads();
    #pragma unroll 8
    for (int k = 0; k < 32; ++k){
      float a[RM], b[8];
      #pragma unroll
      for (int i4 = 0; i4 < RM/4; ++i4)
        *(f32x4*)&a[i4*4] = *(const f32x4*)&As[k][ty*RM + i4*4];
      *(f32x4*)&b[0] = *(const f32x4*)&Bs[k][tx*8];
      *(f32x4*)&b[4] = *(const f32x4*)&Bs[k][tx*8 + 4];
      #pragma unroll
      for (int i = 0; i < RM; ++i)
        #pragma unroll
        for (int j = 0; j < 8; ++j) acc[i][j] += a[i]*b[j];
    }
  }
  #pragma unroll
  for (int i = 0; i < RM; ++i){
    const int row = m0 + ty*RM + i;
    const int col = n0 + tx*8;
    if constexpr (EPI == 0){
      *(f32x4*)&C[(size_t)row*768 + col]     = *(const f32x4*)&acc[i][0];
      *(f32x4*)&C[(size_t)row*768 + col + 4] = *(const f32x4*)&acc[i][4];
    } else if constexpr (EPI == 1){
      const float s = 0.1f * PSUM[row];
      f32x4 z0 = *(const f32x4*)&C[(size_t)row*256 + col];
      f32x4 z1 = *(const f32x4*)&C[(size_t)row*256 + col + 4];
      z0.x += s*acc[i][0]; z0.y += s*acc[i][1]; z0.z += s*acc[i][2]; z0.w += s*acc[i][3];
      z1.x += s*acc[i][4]; z1.y += s*acc[i][5]; z1.z += s*acc[i][6]; z1.w += s*acc[i][7];
      *(f32x4*)&C[(size_t)row*256 + col]     = z0;
      *(f32x4*)&C[(size_t)row*256 + col + 4] = z1;
    } else {
      f32x4 b0 = *(const f32x4*)&bias[col];
      f32x4 b1 = *(const f32x4*)&bias[col + 4];
      f32x4 o0 = {acc[i][0]+b0.x, acc[i][1]+b0.y, acc[i][2]+b0.z, acc[i][3]+b0.w};
      f32x4 o1 = {acc[i][4]+b1.x, acc[i][5]+b1.y, acc[i][6]+b1.z, acc[i][7]+b1.w};
      *(f32x4*)&C[(size_t)row*128 + col]     = o0;
      *(f32x4*)&C[(size_t)row*128 + col + 4] = o1;
    }
  }
}

// ---------------- fp32 flash attention v6 (r13 optimum): Q,P in registers ---
// 512 thr: ty = tid>>6 (wave, rows ty*4..+3), tx = tid&63 (4 keys / 4 dims).
// Q lane-distributed: qreg[r][g] = Q[row][g*64 + lane] (loaded once).
// QK: K staged transposed (conflict-free); A-operand via v_readlane
// (VALU pipe) -> no LDS A-reads. Softmax P stays in registers (lane tx owns
// keys tx*4..+3); PV fetches P via readlane(pp[r][k2], ks*4+kg).
// LDS = one 16.6 KB K/V chunk buffer only. Gate fused.
__launch_bounds__(512, 1)
__global__ void k_attn32(const float* __restrict__ QKV, float* __restrict__ ZF,
                         float* __restrict__ Mm, float* __restrict__ PSUM,
                         const float* __restrict__ Wc, const float* __restrict__ bc){
  __shared__ __align__(16) float KV[16*260];    // KT [d][key] | V [key][d]
  const int tid = threadIdx.x;
  const int tx = tid & 63;
  const int ty = tid >> 6;
  const int batch = blockIdx.x >> 5, qt = blockIdx.x & 31;
  const int nbase = batch*1024 + qt*32;
  const int kv0 = batch*1024;

  float qreg[4][4];                             // Q[row ty*4+r][g*64 + lane]
  #pragma unroll
  for (int r = 0; r < 4; ++r)
    #pragma unroll
    for (int g = 0; g < 4; ++g)
      qreg[r][g] = QKV[(size_t)(nbase + ty*4 + r)*768 + g*64 + tx];

  float O[4][4];
  #pragma unroll
  for (int r = 0; r < 4; ++r)
    #pragma unroll
    for (int j = 0; j < 4; ++j) O[r][j] = 0.f;
  float mr[4] = {-3.0e30f, -3.0e30f, -3.0e30f, -3.0e30f};
  float lr[4] = {0.f, 0.f, 0.f, 0.f};

  for (int t = 0; t < 4; ++t){
    const int kb = kv0 + t*256;
    float S[4][4];
    #pragma unroll
    for (int r = 0; r < 4; ++r)
      #pragma unroll
      for (int e = 0; e < 4; ++e) S[r][e] = 0.f;

    #pragma unroll
    for (int gg = 0; gg < 4; ++gg){             // qreg g-index compile-time
      for (int dcc = 0; dcc < 4; ++dcc){        // runtime: bounds reg pressure
        const int dc = gg*4 + dcc;
        __syncthreads();                        // prev chunk readers done
        #pragma unroll
        for (int i = 0; i < 2; ++i){            // stage K chunk transposed
          const int c = i*512 + tid;
          const int key = c & 255, d4 = c >> 8;
          f32x4 v = *(const f32x4*)&QKV[(size_t)(kb + key)*768 + 256 + dc*16 + d4*4];
          KV[(d4*4+0)*260 + key] = v.x; KV[(d4*4+1)*260 + key] = v.y;
          KV[(d4*4+2)*260 + key] = v.z; KV[(d4*4+3)*260 + key] = v.w;
        }
        __syncthreads();
        #pragma unroll
        for (int k = 0; k < 16; ++k){
          const int ln = dcc*16 + k;            // (dc*16+k)&63, uniform
          const float a0 = rdl(qreg[0][gg], ln);
          const float a1 = rdl(qreg[1][gg], ln);
          const float a2 = rdl(qreg[2][gg], ln);
          const float a3 = rdl(qreg[3][gg], ln);
          const f32x4 b = *(const f32x4*)&KV[k*260 + tx*4];
          S[0][0] += a0*b.x; S[0][1] += a0*b.y; S[0][2] += a0*b.z; S[0][3] += a0*b.w;
          S[1][0] += a1*b.x; S[1][1] += a1*b.y; S[1][2] += a1*b.z; S[1][3] += a1*b.w;
          S[2][0] += a2*b.x; S[2][1] += a2*b.y; S[2][2] += a2*b.z; S[2][3] += a2*b.w;
          S[3][0] += a3*b.x; S[3][1] += a3*b.y; S[3][2] += a3*b.z; S[3][3] += a3*b.w;
        }
      }
    }
    // ---- online softmax: row = wave (lane tx owns keys tx*4..+3) ----
    float pp[4][4];
    #pragma unroll
    for (int r = 0; r < 4; ++r){
      #pragma unroll
      for (int e = 0; e < 4; ++e) S[r][e] *= QK_SCALE;
      float tm = fmaxf(fmaxf(S[r][0], S[r][1]), fmaxf(S[r][2], S[r][3]));
      tm = fmaxf(tm, __shfl_xor(tm, 1));
      tm = fmaxf(tm, __shfl_xor(tm, 2));
      tm = fmaxf(tm, __shfl_xor(tm, 4));
      tm = fmaxf(tm, __shfl_xor(tm, 8));
      tm = fmaxf(tm, __shfl_xor(tm, 16));
      tm = fmaxf(tm, __shfl_xor(tm, 32));
      const float mn = fmaxf(mr[r], tm);
      const float al = expf(mr[r] - mn);
      pp[r][0] = expf(S[r][0] - mn); pp[r][1] = expf(S[r][1] - mn);
      pp[r][2] = expf(S[r][2] - mn); pp[r][3] = expf(S[r][3] - mn);
      float rs = (pp[r][0] + pp[r][1]) + (pp[r][2] + pp[r][3]);
      rs += __shfl_xor(rs, 1); rs += __shfl_xor(rs, 2);
      rs += __shfl_xor(rs, 4); rs += __shfl_xor(rs, 8);
      rs += __shfl_xor(rs, 16); rs += __shfl_xor(rs, 32);
      lr[r] = lr[r]*al + rs;
      mr[r] = mn;
      O[r][0] *= al; O[r][1] *= al; O[r][2] *= al; O[r][3] *= al;
    }
    // ---- PV over 16 chunks of 16 keys; P via readlane ----
    for (int ks = 0; ks < 16; ++ks){
      __syncthreads();                          // prev chunk readers done
      #pragma unroll
      for (int i = 0; i < 2; ++i){              // stage V chunk natural
        const int c = i*512 + tid;
        const int key = c >> 6, d4 = c & 63;
        *(f32x4*)&KV[key*260 + d4*4] =
            *(const f32x4*)&QKV[(size_t)(kb + ks*16 + key)*768 + 512 + d4*4];
      }
      __syncthreads();
      #pragma unroll
      for (int kg = 0; kg < 4; ++kg){
        const int ln = ks*4 + kg;               // lane owning these 4 keys
        #pragma unroll
        for (int k2 = 0; k2 < 4; ++k2){
          const float a0 = rdl(pp[0][k2], ln);
          const float a1 = rdl(pp[1][k2], ln);
          const float a2 = rdl(pp[2][k2], ln);
          const float a3 = rdl(pp[3][k2], ln);
          const f32x4 v = *(const f32x4*)&KV[(kg*4+k2)*260 + tx*4];
          O[0][0] += a0*v.x; O[0][1] += a0*v.y; O[0][2] += a0*v.z; O[0][3] += a0*v.w;
          O[1][0] += a1*v.x; O[1][1] += a1*v.y; O[1][2] += a1*v.z; O[1][3] += a1*v.w;
          O[2][0] += a2*v.x; O[2][1] += a2*v.y; O[2][2] += a2*v.z; O[2][3] += a2*v.w;
          O[3][0] += a3*v.x; O[3][1] += a3*v.y; O[3][2] += a3*v.z; O[3][3] += a3*v.w;
        }
      }
    }
  }
  // ---- epilogue: normalize + fused gate + memory/pointer update ----
  const float bc0 = bc[0], bc1 = bc[1], bc2 = bc[2];
  #pragma unroll
  for (int r = 0; r < 4; ++r){
    const float inv = 1.f / lr[r];
    #pragma unroll
    for (int j = 0; j < 4; ++j) O[r][j] *= inv;
    float d0 = 0.f, d1 = 0.f, d2 = 0.f;
    #pragma unroll
    for (int j = 0; j < 4; ++j){
      const int dim = tx*4 + j;
      const float z = O[r][j];
      d0 += z*Wc[dim*3 + 0]; d1 += z*Wc[dim*3 + 1]; d2 += z*Wc[dim*3 + 2];
    }
    d0 += __shfl_xor(d0,1); d0 += __shfl_xor(d0,2); d0 += __shfl_xor(d0,4);
    d0 += __shfl_xor(d0,8); d0 += __shfl_xor(d0,16); d0 += __shfl_xor(d0,32);
    d1 += __shfl_xor(d1,1); d1 += __shfl_xor(d1,2); d1 += __shfl_xor(d1,4);
    d1 += __shfl_xor(d1,8); d1 += __shfl_xor(d1,16); d1 += __shfl_xor(d1,32);
    d2 += __shfl_xor(d2,1); d2 += __shfl_xor(d2,2); d2 += __shfl_xor(d2,4);
    d2 += __shfl_xor(d2,8); d2 += __shfl_xor(d2,16); d2 += __shfl_xor(d2,32);
    const float g0 = 1.f/(1.f + expf(-(d0 + bc0)));
    const float g1 = 1.f/(1.f + expf(-(d1 + bc1)));
    const float g2 = 1.f/(1.f + expf(-(d2 + bc2)));
    const float tt = g0 + g1 + g2, tot = tt + 1e-6f;
    const float push = g0/tot;
    const int row = nbase + ty*4 + r;
    if (tx == 0) PSUM[row] *= tt/tot;
    const size_t idx = (size_t)row*256 + tx*4;
    f32x4 z0 = {O[r][0], O[r][1], O[r][2], O[r][3]};
    f32x4 m0 = *(const f32x4*)&Mm[idx];
    m0.x += push*(z0.x - m0.x); m0.y += push*(z0.y - m0.y);
    m0.z += push*(z0.z - m0.z); m0.w += push*(z0.w - m0.w);
    *(f32x4*)&Mm[idx] = m0;
    *(f32x4*)&ZF[idx] = z0;
  }
}

// ---------------------------------------------------------------------------
extern "C" void kernel_launch(void* const* d_in, const int* in_sizes, int n_in,
                              void* d_out, int out_size, void* d_ws, size_t ws_size,
                              hipStream_t stream){
  (void)in_sizes; (void)n_in; (void)out_size; (void)ws_size;
  const float* xr   = (const float*)d_in[0];
  const float* xi   = (const float*)d_in[1];
  const float* Wq_r = (const float*)d_in[2];
  const float* Wq_i = (const float*)d_in[3];
  const float* Wk_r = (const float*)d_in[4];
  const float* Wk_i = (const float*)d_in[5];
  const float* Wv_r = (const float*)d_in[6];
  const float* Wv_i = (const float*)d_in[7];
  // d_in[8..11] (Mq_*, Mk_*) unused: all stack slots identical -> memory
  // attention exactly uniform regardless of its q/k projections (verified r3).
  const float* Mv_r = (const float*)d_in[12];
  const float* Mv_i = (const float*)d_in[13];
  const float* Wc   = (const float*)d_in[14];
  const float* bc   = (const float*)d_in[15];
  const float* Wo   = (const float*)d_in[16];
  const float* bo   = (const float*)d_in[17];

  // Workspace layout identical to verified round 3/6 (41,975,808 B).
  uint8_t* w = (uint8_t*)d_ws;
  float* Z    = (float*)w; w += (size_t)8192*256*4;   // state; aliased as ZF
  float* QKV  = (float*)w; w += (size_t)8192*768*4;
  float* Mm   = (float*)w; w += (size_t)8192*256*4;
  float* PSUM = (float*)w; w += (size_t)8192*4;
  float* ZF   = Z;  // safe alias: state dead once proj consumed it.

  k_init32<<<dim3(1024), dim3(256), 0, stream>>>(xr, xi, Z, Mm, PSUM);
  for (int t = 0; t < 8; ++t){
    k_gemm32<0,64><<<dim3(768), dim3(256), 0, stream>>>(Z, 6,
        Wq_r, Wq_i, Wk_r, Wk_i, Wv_r, Wv_i, QKV, nullptr, nullptr);
    k_attn32<<<dim3(256), dim3(512), 0, stream>>>(QKV, ZF, Mm, PSUM, Wc, bc);
    k_gemm32<1,64><<<dim3(256), dim3(256), 0, stream>>>(Mm, 2,
        Mv_r, Mv_i, nullptr, nullptr, nullptr, nullptr, Z, PSUM, nullptr);
  }
  k_gemm32<2,128><<<dim3(64), dim3(256), 0, stream>>>(Z, 1,
      Wo, nullptr, nullptr, nullptr, nullptr, nullptr, (float*)d_out, nullptr, bo);
}